// Round 3
// baseline (7677.525 us; speedup 1.0000x reference)
//
#include <hip/hip_runtime.h>

#define NB 4
#define NPER 8192
#define MPER 2048
#define KNN 16
#define CIN 64
#define CO 128
#define MTOT (NB*MPER)
#define NCELL 64
#define CSZ 128

typedef unsigned long long u64;
typedef unsigned int u32;
typedef unsigned short u16;

__device__ __forceinline__ float med3f(float a, float b, float c) {
    return __builtin_amdgcn_fmed3f(a, b, c);
}

// ---------------- init: zero stats + write row_splits ----------------
__global__ void k_init(float* __restrict__ stats, float* __restrict__ rs) {
    int t = threadIdx.x;
    if (t < 256) stats[t] = 0.f;
    if (t < 5) rs[t] = (float)(t * MPER);
}

// DPP compare-select step on a packed u64 key (max). Masked-out lanes keep old.
#define DPPSTEP(key, CTRL, RM) do {                                                   \
    unsigned lo_ = (unsigned)(key), hi_ = (unsigned)((key) >> 32);                    \
    unsigned nlo = (unsigned)__builtin_amdgcn_update_dpp((int)lo_, (int)lo_, CTRL, RM, 0xf, false); \
    unsigned nhi = (unsigned)__builtin_amdgcn_update_dpp((int)hi_, (int)hi_, CTRL, RM, 0xf, false); \
    unsigned long long ok_ = ((unsigned long long)nhi << 32) | nlo;                   \
    if (ok_ > (key)) (key) = ok_;                                                     \
} while (0)

#define DPP6(key) do { \
    DPPSTEP(key, 0xB1,  0xF); \
    DPPSTEP(key, 0x4E,  0xF); \
    DPPSTEP(key, 0x141, 0xF); \
    DPPSTEP(key, 0x140, 0xF); \
    DPPSTEP(key, 0x142, 0xA); \
    DPPSTEP(key, 0x143, 0xC); \
} while (0)

// ---------------- FPS: lazy bucketed, one block per batch ----------------
__launch_bounds__(256, 1)
__global__ void k_fps(const float* __restrict__ pts, float* __restrict__ out_np,
                      float4* __restrict__ qpts) {
    #pragma clang fp contract(off)
    __shared__ float spx[NPER], spy[NPER], spz[NPER];   // 96KB sorted coords
    __shared__ u32   sdu[NPER];                          // 32KB: morton keys, then dist
    __shared__ u16   sorig[NPER];                        // 16KB original index per slot
    __shared__ u16   cent[MPER];                         // 4KB centroid slots
    __shared__ u64   skey[NCELL];                        // packed (maxdist, ~idx) per cell
    __shared__ u32   lastA[NCELL];                       // last applied centroid count
    __shared__ float bbl[6][NCELL];                      // cell bbox: xm,ym,zm,xM,yM,zM
    __shared__ float4 survbuf[64];
    __shared__ u64   stalebits;
    __shared__ float gb[4][6];
    __shared__ int   slot0sh;
    float* sdist = (float*)sdu;

    const int b = blockIdx.x;
    const int t = threadIdx.x;
    const float* pb = pts + (size_t)b * NPER * 3;

    // --- pass A: global bbox ---
    float mnx=1e30f,mny=1e30f,mnz=1e30f,mxx=-1e30f,mxy=-1e30f,mxz=-1e30f;
    for (int s = t; s < NPER; s += 256) {
        float x=pb[s*3], y=pb[s*3+1], z=pb[s*3+2];
        mnx=fminf(mnx,x); mxx=fmaxf(mxx,x);
        mny=fminf(mny,y); mxy=fmaxf(mxy,y);
        mnz=fminf(mnz,z); mxz=fmaxf(mxz,z);
    }
    #pragma unroll
    for (int off=1; off<64; off<<=1) {
        mnx=fminf(mnx,__shfl_xor(mnx,off)); mxx=fmaxf(mxx,__shfl_xor(mxx,off));
        mny=fminf(mny,__shfl_xor(mny,off)); mxy=fmaxf(mxy,__shfl_xor(mxy,off));
        mnz=fminf(mnz,__shfl_xor(mnz,off)); mxz=fmaxf(mxz,__shfl_xor(mxz,off));
    }
    if ((t&63)==0) {
        int w = t>>6;
        gb[w][0]=mnx; gb[w][1]=mny; gb[w][2]=mnz; gb[w][3]=mxx; gb[w][4]=mxy; gb[w][5]=mxz;
    }
    __syncthreads();
    mnx=fminf(fminf(gb[0][0],gb[1][0]),fminf(gb[2][0],gb[3][0]));
    mny=fminf(fminf(gb[0][1],gb[1][1]),fminf(gb[2][1],gb[3][1]));
    mnz=fminf(fminf(gb[0][2],gb[1][2]),fminf(gb[2][2],gb[3][2]));
    mxx=fmaxf(fmaxf(gb[0][3],gb[1][3]),fmaxf(gb[2][3],gb[3][3]));
    mxy=fmaxf(fmaxf(gb[0][4],gb[1][4]),fmaxf(gb[2][4],gb[3][4]));
    mxz=fmaxf(fmaxf(gb[0][5],gb[1][5]),fmaxf(gb[2][5],gb[3][5]));
    float scx = 63.0f / fmaxf(mxx-mnx, 1e-20f);
    float scy = 63.0f / fmaxf(mxy-mny, 1e-20f);
    float scz = 63.0f / fmaxf(mxz-mnz, 1e-20f);

    // --- pass B: morton keys ---
    for (int s = t; s < NPER; s += 256) {
        float x=pb[s*3], y=pb[s*3+1], z=pb[s*3+2];
        u32 qx = (u32)min(63, max(0, (int)((x-mnx)*scx)));
        u32 qy = (u32)min(63, max(0, (int)((y-mny)*scy)));
        u32 qz = (u32)min(63, max(0, (int)((z-mnz)*scz)));
        u32 mx_=qx, my_=qy, mz_=qz;
        #define P1B2(v) do { v=(v|(v<<8))&0x0300F00Fu; v=(v|(v<<4))&0x030C30C3u; v=(v|(v<<2))&0x09249249u; } while(0)
        P1B2(mx_); P1B2(my_); P1B2(mz_);
        u32 m = (mx_<<2)|(my_<<1)|mz_;    // 18 bits
        sdu[s] = (m << 13) | (u32)s;
    }
    __syncthreads();

    // --- bitonic sort ascending on sdu ---
    for (u32 kk2 = 2; kk2 <= NPER; kk2 <<= 1) {
        for (u32 j = kk2 >> 1; j > 0; j >>= 1) {
            for (int ii = t; ii < NPER; ii += 256) {
                int l = ii ^ (int)j;
                if (l > ii) {
                    u32 a = sdu[ii], bb = sdu[l];
                    bool asc = ((ii & (int)kk2) == 0);
                    if ((a > bb) == asc) { sdu[ii] = bb; sdu[l] = a; }
                }
            }
            __syncthreads();
        }
    }

    // --- scatter sorted coords, init dist ---
    for (int s = t; s < NPER; s += 256) {
        u32 v = sdu[s];
        u32 orig = v & 0x1FFFu;
        float x=pb[orig*3], y=pb[orig*3+1], z=pb[orig*3+2];
        spx[s]=x; spy[s]=y; spz[s]=z;
        sorig[s]=(u16)orig;
        if (orig == 0) slot0sh = s;
        sdist[s] = 1e10f;   // own slot: safe to overwrite after read
    }
    __syncthreads();

    // --- per-cell bbox (wave per 16 cells) ---
    {
        int w = t >> 6, lane = t & 63;
        for (int c = w*16; c < w*16+16; ++c) {
            int s0 = c*CSZ + lane, s1 = s0 + 64;
            float ax=fminf(spx[s0],spx[s1]), Ax=fmaxf(spx[s0],spx[s1]);
            float ay=fminf(spy[s0],spy[s1]), Ay=fmaxf(spy[s0],spy[s1]);
            float az=fminf(spz[s0],spz[s1]), Az=fmaxf(spz[s0],spz[s1]);
            #pragma unroll
            for (int off=1; off<64; off<<=1) {
                ax=fminf(ax,__shfl_xor(ax,off)); Ax=fmaxf(Ax,__shfl_xor(Ax,off));
                ay=fminf(ay,__shfl_xor(ay,off)); Ay=fmaxf(Ay,__shfl_xor(Ay,off));
                az=fminf(az,__shfl_xor(az,off)); Az=fmaxf(Az,__shfl_xor(Az,off));
            }
            if (lane == 0) {
                bbl[0][c]=ax; bbl[1][c]=ay; bbl[2][c]=az;
                bbl[3][c]=Ax; bbl[4][c]=Ay; bbl[5][c]=Az;
            }
        }
    }
    if (t < NCELL) { skey[t] = (((u64)__float_as_uint(1e10f))<<32) | 0xFFFFFFFFull; lastA[t]=0; }
    __syncthreads();
    if (t == 0) {
        stalebits = ~0ull;
        cent[0] = (u16)slot0sh;
        float nx=spx[slot0sh], ny=spy[slot0sh], nz=spz[slot0sh];
        size_t row = (size_t)b * MPER;
        out_np[row*3+0]=nx; out_np[row*3+1]=ny; out_np[row*3+2]=nz;
        qpts[row] = make_float4(nx,ny,nz,0.f);
    }
    __syncthreads();

    // --- main loop ---
    const int lane = t & 63;
    for (int i = 1; i < MPER; ++i) {
        for (;;) {
            u64 kk = skey[lane];
            u64 rk = kk;
            DPP6(rk);
            u32 tlo = (u32)__builtin_amdgcn_readlane((int)(u32)rk, 63);
            u32 thi = (u32)__builtin_amdgcn_readlane((int)(u32)(rk >> 32), 63);
            u64 topkey = ((u64)thi << 32) | tlo;
            u64 sb = stalebits;
            u64 bal = __ballot(kk == topkey);
            int cell = __ffsll((long long)bal) - 1;
            if (!((sb >> cell) & 1)) {
                // exact top -> winner
                u32 lo = ~(u32)topkey;
                int wslot = (int)(lo & 0x1FFFu);
                float nx=spx[wslot], ny=spy[wslot], nz=spz[wslot];
                if (t == 0) {
                    cent[i] = (u16)wslot;
                    stalebits = ~0ull;
                    size_t row = (size_t)b * MPER + i;
                    out_np[row*3+0]=nx; out_np[row*3+1]=ny; out_np[row*3+2]=nz;
                    qpts[row] = make_float4(nx,ny,nz,0.f);
                }
                break;
            }
            if (t < 64) {   // wave 0 refreshes top stale cell
                float ubv = __uint_as_float((u32)(topkey >> 32));
                float thr = ubv * 1.001f;
                float bx0=bbl[0][cell],by0=bbl[1][cell],bz0=bbl[2][cell];
                float bx1=bbl[3][cell],by1=bbl[4][cell],bz1=bbl[5][cell];
                int s0 = cell*CSZ + lane, s1 = s0 + 64;
                float d0=sdist[s0], d1=sdist[s1];
                float X0=spx[s0],Y0=spy[s0],Z0=spz[s0];
                float X1=spx[s1],Y1=spy[s1],Z1=spz[s1];
                u32 a = lastA[cell];
                for (u32 cb = a; cb < (u32)i; cb += 64) {
                    u32 c = cb + (u32)lane;
                    bool sv = false;
                    float ccx=0.f, ccy=0.f, ccz=0.f;
                    if (c < (u32)i) {
                        int cs = cent[c];
                        ccx=spx[cs]; ccy=spy[cs]; ccz=spz[cs];
                        float ex = fmaxf(fmaxf(bx0-ccx, ccx-bx1), 0.f);
                        float ey = fmaxf(fmaxf(by0-ccy, ccy-by1), 0.f);
                        float ez = fmaxf(fmaxf(bz0-ccz, ccz-bz1), 0.f);
                        float lb = (ex*ex + ey*ey) + ez*ez;
                        sv = (lb <= thr);   // skip only if lb > ub*1.001 (provably no-op)
                    }
                    u64 mask = __ballot(sv);
                    if (sv) {
                        int pos = __popcll(mask & ((1ull << lane) - 1ull));
                        survbuf[pos] = make_float4(ccx,ccy,ccz,0.f);
                    }
                    int ns = __popcll(mask);
                    for (int sI = 0; sI < ns; ++sI) {
                        float4 cc = survbuf[sI];
                        float dx0=X0-cc.x, dy0=Y0-cc.y, dz0=Z0-cc.z;
                        float a0=dx0*dx0, a1=dy0*dy0, a2=dz0*dz0;
                        float dq0=(a0+a1)+a2; d0=fminf(d0,dq0);
                        float dx1=X1-cc.x, dy1=Y1-cc.y, dz1=Z1-cc.z;
                        float b0=dx1*dx1, b1=dy1*dy1, b2=dz1*dz1;
                        float dq1=(b0+b1)+b2; d1=fminf(d1,dq1);
                    }
                }
                sdist[s0]=d0; sdist[s1]=d1;
                u64 k0 = (((u64)__float_as_uint(d0))<<32) | (u32)~((((u32)sorig[s0])<<13)|(u32)s0);
                u64 k1 = (((u64)__float_as_uint(d1))<<32) | (u32)~((((u32)sorig[s1])<<13)|(u32)s1);
                u64 bk = k0 > k1 ? k0 : k1;
                DPP6(bk);
                if (lane == 63) skey[cell] = bk;
                if (lane == 0) { lastA[cell] = (u32)i; stalebits = sb & ~(1ull << cell); }
            }
            __syncthreads();
        }
        __syncthreads();
    }
}

// ---------------- KNN: 256 queries per block ----------------
#define CHUNK 2048
__launch_bounds__(256, 2)
__global__ void k_knn(const float* __restrict__ pts, const float4* __restrict__ qpts,
                      int* __restrict__ nidx) {
    #pragma clang fp contract(off)
    __shared__ float4 sp[CHUNK];
    __shared__ int cand[256][32];
    const int t = threadIdx.x;
    const int q = blockIdx.x * 256 + t;
    const int b = q >> 11;
    const float4 qp = qpts[q];
    const float qq = (qp.x * qp.x + qp.y * qp.y) + qp.z * qp.z;
    const float* pb = pts + (size_t)b * NPER * 3;

    float nd[16];
    #pragma unroll
    for (int j = 0; j < 16; ++j) nd[j] = 1e30f;

    for (int c = 0; c < NPER / CHUNK; ++c) {
        __syncthreads();
        #pragma unroll
        for (int r = 0; r < CHUNK / 256; ++r) {
            int li = r * 256 + t;
            int gi = c * CHUNK + li;
            float x = pb[gi*3], y = pb[gi*3+1], z = pb[gi*3+2];
            float pp = (x * x + y * y) + z * z;
            sp[li] = make_float4(x, y, z, pp);
        }
        __syncthreads();
        #pragma unroll 4
        for (int j = 0; j < CHUNK; ++j) {
            float4 p = sp[j];
            float dot = (qp.x * p.x + qp.y * p.y) + qp.z * p.z;
            float d = (qq + p.w) - 2.f * dot;
            if (d < nd[15]) {
                #pragma unroll
                for (int u = 15; u >= 1; --u) nd[u] = med3f(d, nd[u-1], nd[u]);
                nd[0] = fminf(nd[0], d);
            }
        }
    }
    const float tau = nd[15];

    int cnt = 0, cless = 0;
    for (int c = 0; c < NPER / CHUNK; ++c) {
        __syncthreads();
        #pragma unroll
        for (int r = 0; r < CHUNK / 256; ++r) {
            int li = r * 256 + t;
            int gi = c * CHUNK + li;
            float x = pb[gi*3], y = pb[gi*3+1], z = pb[gi*3+2];
            float pp = (x * x + y * y) + z * z;
            sp[li] = make_float4(x, y, z, pp);
        }
        __syncthreads();
        for (int j = 0; j < CHUNK; ++j) {
            float4 p = sp[j];
            float dot = (qp.x * p.x + qp.y * p.y) + qp.z * p.z;
            float d = (qq + p.w) - 2.f * dot;
            if (d <= tau && cnt < 32) {
                bool eq = !(d < tau);
                cand[t][cnt++] = (c * CHUNK + j) | (eq ? 0x80000000 : 0);
                if (!eq) cless++;
            }
        }
    }
    int quota = 16 - cless, kept = 0, eq_used = 0;
    for (int e = 0; e < cnt && kept < 16; ++e) {
        int v = cand[t][e];
        bool eq = (v & 0x80000000) != 0;
        int pidx = v & 0x7fffffff;
        bool take = !eq || (eq_used < quota);
        if (take) {
            if (eq) eq_used++;
            nidx[(size_t)q * KNN + kept] = b * NPER + pidx;
            kept++;
        }
    }
}

// ---------------- fused gather + linear + stats + k-minmax ----------------
__launch_bounds__(128, 4)
__global__ void k_stats(const float* __restrict__ pts, const float* __restrict__ feat,
                        const float* __restrict__ W, const int* __restrict__ nidx,
                        const float4* __restrict__ qpts, float* __restrict__ ymax,
                        float* __restrict__ ymin, float* __restrict__ stats) {
    __shared__ float4 g4[KNN][17];
    const int t = threadIdx.x;
    float w[68];
    const float* wr = W + t * 67;
    #pragma unroll
    for (int c = 0; c < 64; ++c) w[c] = wr[3 + c];
    w[64] = wr[0]; w[65] = wr[1]; w[66] = wr[2]; w[67] = 0.f;

    float s_sum = 0.f, s_sq = 0.f;
    const int k0 = t >> 3, p8 = t & 7;
    for (int mi = 0; mi < 8; ++mi) {
        const int m0 = blockIdx.x * 8 + mi;
        {
            int nid = nidx[(size_t)m0 * KNN + k0];
            const float4* fr = (const float4*)(feat + (size_t)nid * CIN);
            g4[k0][p8*2]   = fr[p8*2];
            g4[k0][p8*2+1] = fr[p8*2+1];
        }
        if (t < 16) {
            int nid = nidx[(size_t)m0 * KNN + t];
            float4 qp = qpts[m0];
            float x = pts[(size_t)nid*3], y = pts[(size_t)nid*3+1], z = pts[(size_t)nid*3+2];
            g4[t][16] = make_float4(x - qp.x, y - qp.y, z - qp.z, 0.f);
        }
        __syncthreads();
        float vmax = -1e30f, vmin = 1e30f;
        #pragma unroll 1
        for (int k = 0; k < KNN; ++k) {
            float y0 = 0.f, y1 = 0.f, y2 = 0.f, y3 = 0.f;
            #pragma unroll
            for (int c4 = 0; c4 < 17; ++c4) {
                float4 gv = g4[k][c4];
                y0 = fmaf(gv.x, w[c4*4+0], y0);
                y1 = fmaf(gv.y, w[c4*4+1], y1);
                y2 = fmaf(gv.z, w[c4*4+2], y2);
                y3 = fmaf(gv.w, w[c4*4+3], y3);
            }
            float y = (y0 + y1) + (y2 + y3);
            vmax = fmaxf(vmax, y); vmin = fminf(vmin, y);
            s_sum += y; s_sq = fmaf(y, y, s_sq);
        }
        ymax[(size_t)m0 * CO + t] = vmax;
        ymin[(size_t)m0 * CO + t] = vmin;
        __syncthreads();
    }
    atomicAdd(stats + t, s_sum);
    atomicAdd(stats + CO + t, s_sq);
}

// ---------------- finalize BN scale/shift ----------------
__global__ void k_final(const float* __restrict__ stats, const float* __restrict__ gamma,
                        const float* __restrict__ beta, float* __restrict__ sb) {
    int o = threadIdx.x;
    const float inv = 1.f / (float)(MTOT * KNN);
    float mean = stats[o] * inv;
    float var = stats[CO + o] * inv - mean * mean;
    var = fmaxf(var, 0.f);
    float s = gamma[o] * rsqrtf(var + 1e-5f);
    sb[o] = s;
    sb[CO + o] = beta[o] - mean * s;
}

// ---------------- epilogue: relu(s*ext + b) ----------------
__global__ void k_out(const float* __restrict__ ymax, const float* __restrict__ ymin,
                      const float* __restrict__ sb, float* __restrict__ out_feat) {
    int tid = blockIdx.x * 256 + threadIdx.x;
    int o = tid & (CO - 1);
    float s = sb[o], bb = sb[CO + o];
    float yv = (s >= 0.f) ? ymax[tid] : ymin[tid];
    out_feat[tid] = fmaxf(fmaf(s, yv, bb), 0.f);
}

extern "C" void kernel_launch(void* const* d_in, const int* in_sizes, int n_in,
                              void* d_out, int out_size, void* d_ws, size_t ws_size,
                              hipStream_t stream) {
    const float* pts   = (const float*)d_in[0];
    const float* feat  = (const float*)d_in[1];
    const float* W     = (const float*)d_in[3];
    const float* gamma = (const float*)d_in[4];
    const float* beta  = (const float*)d_in[5];
    float* out = (float*)d_out;
    char* ws = (char*)d_ws;

    float4* qpts = (float4*)(ws);                       // 131072 B
    int*    nidx = (int*)(ws + 131072);                 // 524288 B
    float*  stats = (float*)(ws + 655360);              // 1024 B
    float*  sb    = (float*)(ws + 656384);              // 1024 B
    float*  ymax  = (float*)(ws + 657408);              // 4 MB
    float*  ymin  = (float*)(ws + 657408 + 4194304);    // 4 MB

    float* out_np   = out;                    // (8192,3)
    float* out_feat = out + 24576;            // (8192,128)
    float* out_rs   = out + 24576 + 1048576;  // (5,)

    hipLaunchKernelGGL(k_init,  dim3(1), dim3(256), 0, stream, stats, out_rs);
    hipLaunchKernelGGL(k_fps,   dim3(NB), dim3(256), 0, stream, pts, out_np, qpts);
    hipLaunchKernelGGL(k_knn,   dim3(MTOT / 256), dim3(256), 0, stream, pts, qpts, nidx);
    hipLaunchKernelGGL(k_stats, dim3(MTOT / 8), dim3(128), 0, stream,
                       pts, feat, W, nidx, qpts, ymax, ymin, stats);
    hipLaunchKernelGGL(k_final, dim3(1), dim3(128), 0, stream, stats, gamma, beta, sb);
    hipLaunchKernelGGL(k_out,   dim3(MTOT * CO / 256), dim3(256), 0, stream,
                       ymax, ymin, sb, out_feat);
}

// Round 4
// 2458.062 us; speedup vs baseline: 3.1234x; 3.1234x over previous
//
#include <hip/hip_runtime.h>

#define NB 4
#define NPER 8192
#define MPER 2048
#define KNN 16
#define CIN 64
#define CO 128
#define MTOT (NB*MPER)

typedef unsigned long long u64;
typedef unsigned int u32;

__device__ __forceinline__ float med3f(float a, float b, float c) {
    return __builtin_amdgcn_fmed3f(a, b, c);
}

// ---------------- init: zero stats + write row_splits ----------------
__global__ void k_init(float* __restrict__ stats, float* __restrict__ rs) {
    int t = threadIdx.x;
    if (t < 256) stats[t] = 0.f;
    if (t < 5) rs[t] = (float)(t * MPER);
}

// DPP compare-select step on a packed u64 key (max).
#define DPPSTEP(key, CTRL, RM) do {                                                   \
    unsigned lo_ = (unsigned)(key), hi_ = (unsigned)((key) >> 32);                    \
    unsigned nlo = (unsigned)__builtin_amdgcn_update_dpp((int)lo_, (int)lo_, CTRL, RM, 0xf, false); \
    unsigned nhi = (unsigned)__builtin_amdgcn_update_dpp((int)hi_, (int)hi_, CTRL, RM, 0xf, false); \
    unsigned long long ok_ = ((unsigned long long)nhi << 32) | nlo;                   \
    if (ok_ > (key)) (key) = ok_;                                                     \
} while (0)

#define DPP6(key) do { \
    DPPSTEP(key, 0xB1,  0xF); \
    DPPSTEP(key, 0x4E,  0xF); \
    DPPSTEP(key, 0x141, 0xF); \
    DPPSTEP(key, 0x140, 0xF); \
    DPPSTEP(key, 0x142, 0xA); \
    DPPSTEP(key, 0x143, 0xC); \
} while (0)

// ---------------- FPS: one block per batch, 512 threads, 16 pts/lane ----------------
__launch_bounds__(512, 2)
__global__ void k_fps(const float* __restrict__ pts, float* __restrict__ out_np,
                      float4* __restrict__ qpts) {
    #pragma clang fp contract(off)
    __shared__ float4 spt[NPER];                 // 128 KiB point table (x,y,z,0)
    __shared__ u64 red[2][8];                    // parity-double-buffered wave partials
    const int b = blockIdx.x;
    const int t = threadIdx.x;
    const float4* pb4 = (const float4*)(pts + (size_t)b * NPER * 3);

    // load my 16 points (48 floats = 12 float4) straight into registers
    float f[48];
    #pragma unroll
    for (int j = 0; j < 12; ++j) {
        float4 v = pb4[t * 12 + j];
        f[j*4+0] = v.x; f[j*4+1] = v.y; f[j*4+2] = v.z; f[j*4+3] = v.w;
    }
    float px[16], py[16], pz[16], dd[16];
    #pragma unroll
    for (int s = 0; s < 16; ++s) {
        px[s] = f[3*s]; py[s] = f[3*s+1]; pz[s] = f[3*s+2];
        dd[s] = 1e10f;
        spt[t * 16 + s] = make_float4(px[s], py[s], pz[s], 0.f);
    }
    if (t == 0) {
        size_t row = (size_t)b * MPER;
        out_np[row*3+0] = px[0]; out_np[row*3+1] = py[0]; out_np[row*3+2] = pz[0];
        qpts[row] = make_float4(px[0], py[0], pz[0], 0.f);
    }
    __syncthreads();

    float4 c0 = spt[0];
    float cx = c0.x, cy = c0.y, cz = c0.z;
    const int ibase = t * 16;

    for (int i = 1; i < MPER; ++i) {
        // local argmax over my 16 slots (exact ref arithmetic, strict > keeps lowest idx)
        float bv = -1.f; int bs = 0;
        #pragma unroll
        for (int s = 0; s < 16; ++s) {
            float dx = px[s] - cx, dy = py[s] - cy, dz = pz[s] - cz;
            float t0 = dx * dx, t1 = dy * dy, t2 = dz * dz;
            float d = (t0 + t1) + t2;
            float nd = fminf(dd[s], d);
            dd[s] = nd;
            bool bet = nd > bv;
            bv = bet ? nd : bv;
            bs = bet ? s : bs;
        }
        u64 key = ((u64)__float_as_uint(bv) << 32) | (u32)~(u32)(ibase + bs);

        DPP6(key);   // 64-lane max, full result in lane 63

        if ((t & 63) == 63) red[i & 1][t >> 6] = key;
        __syncthreads();            // single barrier; parity buffer avoids WAW

        const int p = i & 1;
        u64 k0 = red[p][0], k1 = red[p][1], k2 = red[p][2], k3 = red[p][3];
        u64 k4 = red[p][4], k5 = red[p][5], k6 = red[p][6], k7 = red[p][7];
        u64 a0 = k0 > k1 ? k0 : k1, a1 = k2 > k3 ? k2 : k3;
        u64 a2 = k4 > k5 ? k4 : k5, a3 = k6 > k7 ? k6 : k7;
        u64 b0 = a0 > a1 ? a0 : a1, b1 = a2 > a3 ? a2 : a3;
        u64 kbest = b0 > b1 ? b0 : b1;
        const int i2 = (int)(~(u32)kbest & 0x1FFFu);

        float4 c = spt[i2];
        cx = c.x; cy = c.y; cz = c.z;

        if (t == 0) {
            size_t row = (size_t)b * MPER + i;
            out_np[row*3+0] = cx; out_np[row*3+1] = cy; out_np[row*3+2] = cz;
            qpts[row] = make_float4(cx, cy, cz, 0.f);
        }
    }
}

// ---------------- KNN: 64 queries/block, 4 lanes/query ----------------
#define CCAP 28
__launch_bounds__(256, 1)
__global__ void k_knn(const float* __restrict__ pts, const float4* __restrict__ qpts,
                      int* __restrict__ nidx) {
    #pragma clang fp contract(off)
    __shared__ float4 sp[2][4][514];     // [buf][quarter][pt], padded for banks
    __shared__ float  ndl[256][16];
    __shared__ u32    candl[256][CCAP];
    __shared__ int    ccnt[256], ccless[256];
    __shared__ float  taub[64];

    const int t = threadIdx.x;
    const int qloc = t >> 2, sub = t & 3;
    const int q = blockIdx.x * 64 + qloc;
    const int b = q >> 11;
    const float4 qp = qpts[q];
    const float qq = (qp.x * qp.x + qp.y * qp.y) + qp.z * qp.z;
    const float* pb = pts + (size_t)b * NPER * 3;
    const int wq = t >> 6, wl = t & 63;   // staging: wave wq fills quarter wq

    float4 L[6];   // prefetched chunk: my 8 points (24 floats)
    #define LOADC(c) do { const float4* src_ = (const float4*)(pb + (size_t)(c) * 2048 * 3); \
        _Pragma("unroll") for (int u_ = 0; u_ < 6; ++u_) L[u_] = src_[t * 6 + u_]; } while (0)
    #define WRITEC(pbuf) do { \
        float fl_[24]; \
        _Pragma("unroll") for (int u_ = 0; u_ < 6; ++u_) { \
            fl_[u_*4+0]=L[u_].x; fl_[u_*4+1]=L[u_].y; fl_[u_*4+2]=L[u_].z; fl_[u_*4+3]=L[u_].w; } \
        _Pragma("unroll") for (int r_ = 0; r_ < 8; ++r_) { \
            float x_=fl_[3*r_], y_=fl_[3*r_+1], z_=fl_[3*r_+2]; \
            float pp_=(x_*x_ + y_*y_) + z_*z_; \
            sp[pbuf][wq][wl*8 + r_] = make_float4(x_,y_,z_,pp_); } } while (0)

    // ---- pass 1: per-lane sorted top-16 distances over my 2048-pt stream ----
    float nd[16];
    #pragma unroll
    for (int j = 0; j < 16; ++j) nd[j] = 1e30f;

    LOADC(0); WRITEC(0); LOADC(1);
    __syncthreads();
    for (int c = 0; c < 4; ++c) {
        const int pbuf = c & 1;
        #pragma unroll 4
        for (int j = 0; j < 512; ++j) {
            float4 p = sp[pbuf][sub][j];
            float dot = (qp.x * p.x + qp.y * p.y) + qp.z * p.z;
            float d = (qq + p.w) - 2.f * dot;
            if (d < nd[15]) {
                #pragma unroll
                for (int u = 15; u >= 1; --u) nd[u] = med3f(d, nd[u-1], nd[u]);
                nd[0] = fminf(nd[0], d);
            }
        }
        __syncthreads();
        if (c < 3) {
            WRITEC((c + 1) & 1);
            if (c < 2) LOADC(c + 2);
            __syncthreads();
        }
    }
    #pragma unroll
    for (int j = 0; j < 16; ++j) ndl[t][j] = nd[j];
    __syncthreads();

    // leader: exact 16th-smallest via 4-way merge of sorted lists
    if (sub == 0) {
        int p0=0,p1=0,p2=0,p3=0;
        float c0=ndl[t][0], c1=ndl[t+1][0], c2=ndl[t+2][0], c3=ndl[t+3][0];
        float tau = 0.f;
        for (int it = 0; it < 16; ++it) {
            if (c0 <= c1 && c0 <= c2 && c0 <= c3) { tau=c0; ++p0; c0 = (p0<16)?ndl[t][p0]:1e30f; }
            else if (c1 <= c2 && c1 <= c3)        { tau=c1; ++p1; c1 = (p1<16)?ndl[t+1][p1]:1e30f; }
            else if (c2 <= c3)                    { tau=c2; ++p2; c2 = (p2<16)?ndl[t+2][p2]:1e30f; }
            else                                  { tau=c3; ++p3; c3 = (p3<16)?ndl[t+3][p3]:1e30f; }
        }
        taub[qloc] = tau;
    }
    __syncthreads();
    const float tau = taub[qloc];

    // ---- pass 2: collect indices with d <= tau (bit-identical recompute) ----
    int cnt = 0, cless = 0;
    LOADC(0); WRITEC(0); LOADC(1);
    __syncthreads();
    for (int c = 0; c < 4; ++c) {
        const int pbuf = c & 1;
        for (int j = 0; j < 512; ++j) {
            float4 p = sp[pbuf][sub][j];
            float dot = (qp.x * p.x + qp.y * p.y) + qp.z * p.z;
            float d = (qq + p.w) - 2.f * dot;
            if (d <= tau && cnt < CCAP) {
                bool eq = !(d < tau);
                candl[t][cnt++] = (u32)(c * 2048 + sub * 512 + j) | (eq ? 0x80000000u : 0u);
                if (!eq) cless++;
            }
        }
        __syncthreads();
        if (c < 3) {
            WRITEC((c + 1) & 1);
            if (c < 2) LOADC(c + 2);
            __syncthreads();
        }
    }
    ccnt[t] = cnt; ccless[t] = cless;
    __syncthreads();

    // leader: merge 4 candidate streams in ascending point-index order; quota select
    if (sub == 0) {
        int n0=ccnt[t], n1=ccnt[t+1], n2=ccnt[t+2], n3=ccnt[t+3];
        int quota = 16 - (ccless[t]+ccless[t+1]+ccless[t+2]+ccless[t+3]);
        int p0=0,p1=0,p2=0,p3=0, kept=0, eq_used=0;
        u32 h0 = n0 ? candl[t][0]   : 0xFFFFFFFFu;
        u32 h1 = n1 ? candl[t+1][0] : 0xFFFFFFFFu;
        u32 h2 = n2 ? candl[t+2][0] : 0xFFFFFFFFu;
        u32 h3 = n3 ? candl[t+3][0] : 0xFFFFFFFFu;
        size_t obase = (size_t)q * KNN;
        for (int g = 0; g < 4*CCAP && kept < 16; ++g) {
            u32 m0 = h0 & 0x7fffffffu, m1 = h1 & 0x7fffffffu;
            u32 m2 = h2 & 0x7fffffffu, m3 = h3 & 0x7fffffffu;
            u32 v;
            if (m0 <= m1 && m0 <= m2 && m0 <= m3) { v=h0; ++p0; h0 = (p0<n0)?candl[t][p0]:0xFFFFFFFFu; }
            else if (m1 <= m2 && m1 <= m3)        { v=h1; ++p1; h1 = (p1<n1)?candl[t+1][p1]:0xFFFFFFFFu; }
            else if (m2 <= m3)                    { v=h2; ++p2; h2 = (p2<n2)?candl[t+2][p2]:0xFFFFFFFFu; }
            else                                  { v=h3; ++p3; h3 = (p3<n3)?candl[t+3][p3]:0xFFFFFFFFu; }
            if (v == 0xFFFFFFFFu) break;
            bool eq = (v >> 31) != 0;
            bool take = !eq || (eq_used < quota);
            if (take) {
                if (eq) ++eq_used;
                nidx[obase + kept] = b * NPER + (int)(v & 0x7fffffffu);
                ++kept;
            }
        }
    }
    #undef LOADC
    #undef WRITEC
}

// ---------------- fused gather + linear + stats + k-minmax ----------------
__launch_bounds__(128, 4)
__global__ void k_stats(const float* __restrict__ pts, const float* __restrict__ feat,
                        const float* __restrict__ W, const int* __restrict__ nidx,
                        const float4* __restrict__ qpts, float* __restrict__ ymax,
                        float* __restrict__ ymin, float* __restrict__ stats) {
    __shared__ float4 g4[KNN][17];
    const int t = threadIdx.x;
    float w[68];
    const float* wr = W + t * 67;
    #pragma unroll
    for (int c = 0; c < 64; ++c) w[c] = wr[3 + c];
    w[64] = wr[0]; w[65] = wr[1]; w[66] = wr[2]; w[67] = 0.f;

    float s_sum = 0.f, s_sq = 0.f;
    const int k0 = t >> 3, p8 = t & 7;
    for (int mi = 0; mi < 8; ++mi) {
        const int m0 = blockIdx.x * 8 + mi;
        {
            int nid = nidx[(size_t)m0 * KNN + k0];
            const float4* fr = (const float4*)(feat + (size_t)nid * CIN);
            g4[k0][p8*2]   = fr[p8*2];
            g4[k0][p8*2+1] = fr[p8*2+1];
        }
        if (t < 16) {
            int nid = nidx[(size_t)m0 * KNN + t];
            float4 qp = qpts[m0];
            float x = pts[(size_t)nid*3], y = pts[(size_t)nid*3+1], z = pts[(size_t)nid*3+2];
            g4[t][16] = make_float4(x - qp.x, y - qp.y, z - qp.z, 0.f);
        }
        __syncthreads();
        float vmax = -1e30f, vmin = 1e30f;
        #pragma unroll 1
        for (int k = 0; k < KNN; ++k) {
            float y0 = 0.f, y1 = 0.f, y2 = 0.f, y3 = 0.f;
            #pragma unroll
            for (int c4 = 0; c4 < 17; ++c4) {
                float4 gv = g4[k][c4];
                y0 = fmaf(gv.x, w[c4*4+0], y0);
                y1 = fmaf(gv.y, w[c4*4+1], y1);
                y2 = fmaf(gv.z, w[c4*4+2], y2);
                y3 = fmaf(gv.w, w[c4*4+3], y3);
            }
            float y = (y0 + y1) + (y2 + y3);
            vmax = fmaxf(vmax, y); vmin = fminf(vmin, y);
            s_sum += y; s_sq = fmaf(y, y, s_sq);
        }
        ymax[(size_t)m0 * CO + t] = vmax;
        ymin[(size_t)m0 * CO + t] = vmin;
        __syncthreads();
    }
    atomicAdd(stats + t, s_sum);
    atomicAdd(stats + CO + t, s_sq);
}

// ---------------- finalize BN scale/shift ----------------
__global__ void k_final(const float* __restrict__ stats, const float* __restrict__ gamma,
                        const float* __restrict__ beta, float* __restrict__ sb) {
    int o = threadIdx.x;
    const float inv = 1.f / (float)(MTOT * KNN);
    float mean = stats[o] * inv;
    float var = stats[CO + o] * inv - mean * mean;
    var = fmaxf(var, 0.f);
    float s = gamma[o] * rsqrtf(var + 1e-5f);
    sb[o] = s;
    sb[CO + o] = beta[o] - mean * s;
}

// ---------------- epilogue: relu(s*ext + b) ----------------
__global__ void k_out(const float* __restrict__ ymax, const float* __restrict__ ymin,
                      const float* __restrict__ sb, float* __restrict__ out_feat) {
    int tid = blockIdx.x * 256 + threadIdx.x;
    int o = tid & (CO - 1);
    float s = sb[o], bb = sb[CO + o];
    float yv = (s >= 0.f) ? ymax[tid] : ymin[tid];
    out_feat[tid] = fmaxf(fmaf(s, yv, bb), 0.f);
}

extern "C" void kernel_launch(void* const* d_in, const int* in_sizes, int n_in,
                              void* d_out, int out_size, void* d_ws, size_t ws_size,
                              hipStream_t stream) {
    const float* pts   = (const float*)d_in[0];
    const float* feat  = (const float*)d_in[1];
    const float* W     = (const float*)d_in[3];
    const float* gamma = (const float*)d_in[4];
    const float* beta  = (const float*)d_in[5];
    float* out = (float*)d_out;
    char* ws = (char*)d_ws;

    float4* qpts = (float4*)(ws);                       // 131072 B
    int*    nidx = (int*)(ws + 131072);                 // 524288 B
    float*  stats = (float*)(ws + 655360);              // 1024 B
    float*  sb    = (float*)(ws + 656384);              // 1024 B
    float*  ymax  = (float*)(ws + 657408);              // 4 MB
    float*  ymin  = (float*)(ws + 657408 + 4194304);    // 4 MB

    float* out_np   = out;                    // (8192,3)
    float* out_feat = out + 24576;            // (8192,128)
    float* out_rs   = out + 24576 + 1048576;  // (5,)

    hipLaunchKernelGGL(k_init,  dim3(1), dim3(256), 0, stream, stats, out_rs);
    hipLaunchKernelGGL(k_fps,   dim3(NB), dim3(512), 0, stream, pts, out_np, qpts);
    hipLaunchKernelGGL(k_knn,   dim3(MTOT / 64), dim3(256), 0, stream, pts, qpts, nidx);
    hipLaunchKernelGGL(k_stats, dim3(MTOT / 8), dim3(128), 0, stream,
                       pts, feat, W, nidx, qpts, ymax, ymin, stats);
    hipLaunchKernelGGL(k_final, dim3(1), dim3(128), 0, stream, stats, gamma, beta, sb);
    hipLaunchKernelGGL(k_out,   dim3(MTOT * CO / 256), dim3(256), 0, stream,
                       ymax, ymin, sb, out_feat);
}